// Round 14
// baseline (984.851 us; speedup 1.0000x reference)
//
#include <hip/hip_runtime.h>
#include <cstdint>
#include <cstddef>

#define N_NODES 50000
#define N_EDGES 800000
#define IN_DIM 256
#define HID 256
#define EMB 64
#define SCAN_B 1024
#define NBLK ((N_NODES + SCAN_B - 1) / SCAN_B)   // 49
#define BR 64                                     // GEMM rows per block

typedef __attribute__((ext_vector_type(8))) short bf16x8v;   // 8 bf16 in 4 VGPRs
typedef __attribute__((ext_vector_type(4))) float f32x4v;    // MFMA accumulator

// ---- manual bf16 RNE convert ------------------------------------------------
__device__ inline ushort f2bf(float f) {
    uint32_t u = __float_as_uint(f);
    uint32_t r = (u + 0x7FFFu + ((u >> 16) & 1u)) >> 16;
    return (ushort)r;
}
__device__ inline float bf2f(ushort b) {
    return __uint_as_float((uint32_t)b << 16);
}

// ---------------------------------------------------------------------------
// CSR build: histogram -> hierarchical exclusive scan -> fill sorted src list
// ---------------------------------------------------------------------------
__global__ void hist_kernel(const int* __restrict__ dst, int* __restrict__ cnt, int E) {
    int e = blockIdx.x * blockDim.x + threadIdx.x;
    if (e < E) atomicAdd(&cnt[dst[e]], 1);
}

__global__ void scan_local(const int* __restrict__ cnt, int* __restrict__ loc,
                           int* __restrict__ bsum, int n) {
    __shared__ int buf[SCAN_B];
    int tid = threadIdx.x;
    int i = blockIdx.x * SCAN_B + tid;
    int v = (i < n) ? cnt[i] : 0;
    buf[tid] = v;
    __syncthreads();
    #pragma unroll
    for (int off = 1; off < SCAN_B; off <<= 1) {
        int t = (tid >= off) ? buf[tid - off] : 0;
        __syncthreads();
        buf[tid] += t;
        __syncthreads();
    }
    if (i < n) loc[i] = buf[tid] - v;
    if (tid == SCAN_B - 1) bsum[blockIdx.x] = buf[SCAN_B - 1];
}

__global__ void scan_bsum(int* __restrict__ bsum, int nb, int* __restrict__ total_out) {
    __shared__ int b[64];
    int tid = threadIdx.x;
    int v = (tid < nb) ? bsum[tid] : 0;
    b[tid] = v;
    __syncthreads();
    #pragma unroll
    for (int off = 1; off < 64; off <<= 1) {
        int t = (tid >= off) ? b[tid - off] : 0;
        __syncthreads();
        b[tid] += t;
        __syncthreads();
    }
    if (tid < nb) bsum[tid] = b[tid] - v;
    if (tid == 63) *total_out = b[63];
}

__global__ void scan_add(int* __restrict__ loc_cursor, const int* __restrict__ bsum,
                         int* __restrict__ offs, int n) {
    int i = blockIdx.x * SCAN_B + threadIdx.x;
    if (i < n) {
        int o = loc_cursor[i] + bsum[blockIdx.x];
        offs[i] = o;
        loc_cursor[i] = o;
    }
}

__global__ void fill_kernel(const int* __restrict__ src, const int* __restrict__ dst,
                            int* __restrict__ cursor, int* __restrict__ ssrc, int E) {
    int e = blockIdx.x * blockDim.x + threadIdx.x;
    if (e < E) {
        int d = dst[e];
        int pos = atomicAdd(&cursor[d], 1);
        ssrc[pos] = src[e];
    }
}

// ---------------------------------------------------------------------------
// cvt_split: f32 [n] -> bf16 hi + bf16 lo (residual). One thread per 4 elems.
// ---------------------------------------------------------------------------
__global__ void cvt_split(const float* __restrict__ x, ushort* __restrict__ xh,
                          ushort* __restrict__ xl, int n4) {
    int i = blockIdx.x * blockDim.x + threadIdx.x;
    if (i >= n4) return;
    float4 v = ((const float4*)x)[i];
    ushort4 h, l;
    h.x = f2bf(v.x); l.x = f2bf(v.x - bf2f(h.x));
    h.y = f2bf(v.y); l.y = f2bf(v.y - bf2f(h.y));
    h.z = f2bf(v.z); l.z = f2bf(v.z - bf2f(h.z));
    h.w = f2bf(v.w); l.w = f2bf(v.w - bf2f(h.w));
    ((ushort4*)xh)[i] = h;
    ((ushort4*)xl)[i] = l;
}

// ---------------------------------------------------------------------------
// cvt_wT: build transposed+split weight BT[n][k] (k=256) from B1,B2 [256,Nhalf]
// ---------------------------------------------------------------------------
__global__ void cvt_wT(const float* __restrict__ B1, const float* __restrict__ B2,
                       ushort* __restrict__ th, ushort* __restrict__ tl, int Nhalf) {
    int idx = blockIdx.x * blockDim.x + threadIdx.x;   // n*256 + k
    if (idx >= 2 * Nhalf * 256) return;
    int nn = idx >> 8;
    int k  = idx & 255;
    const float* Bp = (nn < Nhalf) ? B1 : B2;
    int col = (nn < Nhalf) ? nn : nn - Nhalf;
    float v = Bp[(size_t)k * Nhalf + col];
    ushort h = f2bf(v);
    th[idx] = h;
    tl[idx] = f2bf(v - bf2f(h));
}

// ---------------------------------------------------------------------------
// bf16x3 split MFMA GEMM v2 — barrier-free main loop.
// A (hi+lo) for BR=64 rows staged ENTIRELY in LDS once (64 KB, one barrier),
// then ncg column-groups of 128 cols computed with zero syncthreads: B frags
// stream from L2 (<=512 KB weights), MFMA pipelines freely.
//   cols <  nsplit -> Cb (bf16, ld=nsplit);  cols >= nsplit -> Cf (f32, ld=ldf)
// Waves 2x2: wave = 32 rows x 64 cols = 2x4 frags, acc 8 f32x4 = 32 AGPR.
// LDS swizzle: 16B slot s stored at s^(row&7) -> fragment reads 2-way = free.
// ---------------------------------------------------------------------------
__global__ __launch_bounds__(256) void gemm_bf16x3_v2(
        const ushort* __restrict__ Ah, const ushort* __restrict__ Al,
        const ushort* __restrict__ BTh, const ushort* __restrict__ BTl,
        ushort* __restrict__ Cb, float* __restrict__ Cf,
        int M, int nsplit, int ldf, int ncg) {
    __shared__ ushort As[2][BR * 256];   // [hi/lo][row*256 + swizzled k], 64 KiB

    int tid  = threadIdx.x;
    int lane = tid & 63;
    int wv   = tid >> 6;        // 0..3
    int wm   = wv >> 1;         // row half (32 rows)
    int wn   = wv & 1;          // col half (64 of 128)
    int rowBase = blockIdx.x * BR;

    // ---- stage all of A for this row-block (one pass, one barrier) ----
    // 4096 uint4 slots total: sm(2) x row(64) x slot(32). 16 per thread.
    #pragma unroll
    for (int i = 0; i < 16; ++i) {
        int gidx = i * 256 + tid;
        int sm   = gidx >> 11;          // /2048
        int rem  = gidx & 2047;
        int row  = rem >> 5;            // /32
        int slot = rem & 31;
        const ushort* Ag = sm ? Al : Ah;
        int gr = rowBase + row;
        uint4 v = (gr < M) ? *(const uint4*)(Ag + (size_t)gr * 256 + slot * 8)
                           : make_uint4(0u, 0u, 0u, 0u);
        *(uint4*)&As[sm][row * 256 + ((slot ^ (row & 7)) * 8)] = v;
    }
    __syncthreads();

    int fr = lane & 15;         // A row-in-frag / B col / C col
    int fc = lane >> 4;         // k-slot (8 elems) / C row group

    for (int cg = 0; cg < ncg; ++cg) {
        f32x4v zero4 = {0.f, 0.f, 0.f, 0.f};
        f32x4v acc[2][4];
        #pragma unroll
        for (int a = 0; a < 2; ++a)
            #pragma unroll
            for (int b = 0; b < 4; ++b) acc[a][b] = zero4;

        #pragma unroll
        for (int k0 = 0; k0 < 8; ++k0) {
            bf16x8v afh[2], afl[2];
            #pragma unroll
            for (int mf = 0; mf < 2; ++mf) {
                int row   = wm * 32 + mf * 16 + fr;
                int kslot = (k0 * 4 + fc) ^ (row & 7);
                int addr  = row * 256 + kslot * 8;
                afh[mf] = *(const bf16x8v*)&As[0][addr];
                afl[mf] = *(const bf16x8v*)&As[1][addr];
            }
            #pragma unroll
            for (int nf = 0; nf < 4; ++nf) {
                int col = cg * 128 + wn * 64 + nf * 16 + fr;
                size_t boff = (size_t)col * 256 + k0 * 32 + fc * 8;
                bf16x8v bfh = *(const bf16x8v*)(BTh + boff);
                bf16x8v bfl = *(const bf16x8v*)(BTl + boff);
                #pragma unroll
                for (int mf = 0; mf < 2; ++mf) {
                    acc[mf][nf] = __builtin_amdgcn_mfma_f32_16x16x32_bf16(
                                      afh[mf], bfh, acc[mf][nf], 0, 0, 0);
                    acc[mf][nf] = __builtin_amdgcn_mfma_f32_16x16x32_bf16(
                                      afh[mf], bfl, acc[mf][nf], 0, 0, 0);
                    acc[mf][nf] = __builtin_amdgcn_mfma_f32_16x16x32_bf16(
                                      afl[mf], bfh, acc[mf][nf], 0, 0, 0);
                }
            }
        }

        // C/D layout (m89-verified): col = lane&15, row = (lane>>4)*4 + reg
        #pragma unroll
        for (int mf = 0; mf < 2; ++mf) {
            #pragma unroll
            for (int nf = 0; nf < 4; ++nf) {
                int col = cg * 128 + wn * 64 + nf * 16 + fr;
                #pragma unroll
                for (int r = 0; r < 4; ++r) {
                    int row = rowBase + wm * 32 + mf * 16 + fc * 4 + r;
                    if (row < M) {
                        float v = acc[mf][nf][r];
                        if (col < nsplit)
                            Cb[(size_t)row * nsplit + col] = f2bf(v);
                        else
                            Cf[(size_t)row * ldf + (col - nsplit)] = v;
                    }
                }
            }
        }
    }
}

// ---------------------------------------------------------------------------
// combine1: h = relu( segmean(t1b) + r1 + b1 ), output split to bf16 hi/lo.
// t1b: [N,256] bf16 (gathered), r1: [N,256] f32 (read once). Wave per node,
// 4 channels per lane (ushort4 = 8B gather per lane), 2-deep unroll.
// ---------------------------------------------------------------------------
__global__ void combine1_kernel(const ushort* __restrict__ t1b,
                                const float* __restrict__ r1,
                                const int* __restrict__ offs,
                                const int* __restrict__ ssrc,
                                const float* __restrict__ b1,
                                ushort* __restrict__ hh, ushort* __restrict__ hl,
                                int n) {
    int gtid = blockIdx.x * blockDim.x + threadIdx.x;
    int node = gtid >> 6;
    int lane = gtid & 63;
    if (node >= n) return;
    int beg = offs[node];
    int end = offs[node + 1];
    const ushort4* t = (const ushort4*)t1b;   // row stride = 64 ushort4
    float4 s = make_float4(0.f, 0.f, 0.f, 0.f);
    int e = beg;
    for (; e + 1 < end; e += 2) {
        int s0 = ssrc[e];
        int s1 = ssrc[e + 1];
        ushort4 q0 = t[(size_t)s0 * 64 + lane];
        ushort4 q1 = t[(size_t)s1 * 64 + lane];
        s.x += bf2f(q0.x) + bf2f(q1.x);
        s.y += bf2f(q0.y) + bf2f(q1.y);
        s.z += bf2f(q0.z) + bf2f(q1.z);
        s.w += bf2f(q0.w) + bf2f(q1.w);
    }
    if (e < end) {
        ushort4 q0 = t[(size_t)ssrc[e] * 64 + lane];
        s.x += bf2f(q0.x); s.y += bf2f(q0.y);
        s.z += bf2f(q0.z); s.w += bf2f(q0.w);
    }
    int deg = end - beg;
    float inv = 1.0f / (float)(deg > 0 ? deg : 1);
    float4 r = ((const float4*)r1)[(size_t)node * 64 + lane];
    float4 bb = ((const float4*)b1)[lane];
    float o0 = s.x * inv + r.x + bb.x;
    float o1 = s.y * inv + r.y + bb.y;
    float o2 = s.z * inv + r.z + bb.z;
    float o3 = s.w * inv + r.w + bb.w;
    o0 = o0 > 0.f ? o0 : 0.f;
    o1 = o1 > 0.f ? o1 : 0.f;
    o2 = o2 > 0.f ? o2 : 0.f;
    o3 = o3 > 0.f ? o3 : 0.f;
    ushort4 h, l;
    h.x = f2bf(o0); l.x = f2bf(o0 - bf2f(h.x));
    h.y = f2bf(o1); l.y = f2bf(o1 - bf2f(h.y));
    h.z = f2bf(o2); l.z = f2bf(o2 - bf2f(h.z));
    h.w = f2bf(o3); l.w = f2bf(o3 - bf2f(h.w));
    ((ushort4*)hh)[(size_t)node * 64 + lane] = h;
    ((ushort4*)hl)[(size_t)node * 64 + lane] = l;
}

// ---------------------------------------------------------------------------
// combine2: emb = segmean(t2b) + r2 + b2. t2b: [N,64] bf16, r2: [N,64] f32.
// Wave per node, scalar channel per lane, 2-deep unroll.
// ---------------------------------------------------------------------------
__global__ void combine2_kernel(const ushort* __restrict__ t2b,
                                const float* __restrict__ r2,
                                const int* __restrict__ offs,
                                const int* __restrict__ ssrc,
                                const float* __restrict__ b2,
                                float* __restrict__ emb, int n) {
    int gtid = blockIdx.x * blockDim.x + threadIdx.x;
    int node = gtid >> 6;
    int lane = gtid & 63;
    if (node >= n) return;
    int beg = offs[node];
    int end = offs[node + 1];
    float s = 0.f;
    int e = beg;
    for (; e + 1 < end; e += 2) {
        int s0 = ssrc[e];
        int s1 = ssrc[e + 1];
        float v0 = bf2f(t2b[(size_t)s0 * 64 + lane]);
        float v1 = bf2f(t2b[(size_t)s1 * 64 + lane]);
        s += v0 + v1;
    }
    if (e < end) s += bf2f(t2b[(size_t)ssrc[e] * 64 + lane]);
    int deg = end - beg;
    float inv = 1.0f / (float)(deg > 0 ? deg : 1);
    emb[(size_t)node * 64 + lane] =
        s * inv + r2[(size_t)node * 64 + lane] + b2[lane];
}

// ---------------------------------------------------------------------------
// Head: out[i] = sigmoid( dot(emb_u[i], W[0:64]) + dot(emb_i[i], W[64:128]) + b )
// ---------------------------------------------------------------------------
__global__ void head_kernel(const float* __restrict__ eu, const float* __restrict__ ei,
                            const float* __restrict__ hW, const float* __restrict__ hb,
                            float* __restrict__ out, int n) {
    __shared__ float w[128];
    __shared__ float b0;
    if (threadIdx.x < 128) w[threadIdx.x] = hW[threadIdx.x];
    if (threadIdx.x == 0) b0 = hb[0];
    __syncthreads();
    int i = blockIdx.x * blockDim.x + threadIdx.x;
    if (i >= n) return;
    const float4* a = (const float4*)(eu + (size_t)i * 64);
    const float4* c = (const float4*)(ei + (size_t)i * 64);
    float s = b0;
    #pragma unroll
    for (int j = 0; j < 16; ++j) {
        float4 v = a[j];
        s += v.x * w[j * 4 + 0] + v.y * w[j * 4 + 1] + v.z * w[j * 4 + 2] + v.w * w[j * 4 + 3];
    }
    #pragma unroll
    for (int j = 0; j < 16; ++j) {
        float4 v = c[j];
        s += v.x * w[64 + j * 4 + 0] + v.y * w[64 + j * 4 + 1] + v.z * w[64 + j * 4 + 2] + v.w * w[64 + j * 4 + 3];
    }
    out[i] = 1.0f / (1.0f + __expf(-s));
}

// ---------------------------------------------------------------------------
extern "C" void kernel_launch(void* const* d_in, const int* in_sizes, int n_in,
                              void* d_out, int out_size, void* d_ws, size_t ws_size,
                              hipStream_t stream) {
    const float* user_x = (const float*)d_in[0];
    const float* item_x = (const float*)d_in[1];
    const int*   u_ei   = (const int*)d_in[2];
    const int*   i_ei   = (const int*)d_in[3];
    const float* u1_Wn = (const float*)d_in[4];
    const float* u1_Wr = (const float*)d_in[5];
    const float* u1_b  = (const float*)d_in[6];
    const float* u2_Wn = (const float*)d_in[7];
    const float* u2_Wr = (const float*)d_in[8];
    const float* u2_b  = (const float*)d_in[9];
    const float* i1_Wn = (const float*)d_in[10];
    const float* i1_Wr = (const float*)d_in[11];
    const float* i1_b  = (const float*)d_in[12];
    const float* i2_Wn = (const float*)d_in[13];
    const float* i2_Wr = (const float*)d_in[14];
    const float* i2_b  = (const float*)d_in[15];
    const float* head_W = (const float*)d_in[16];
    const float* head_b = (const float*)d_in[17];
    float* out = (float*)d_out;

    // Workspace carve-up (256B aligned). Total ~231 MB.
    char* p = (char*)d_ws;
    auto alloc = [&](size_t bytes) -> void* {
        void* r = (void*)p;
        p += (bytes + 255) & ~(size_t)255;
        return r;
    };
    int* cnt_u  = (int*)alloc((size_t)N_NODES * 4);
    int* cnt_i  = (int*)alloc((size_t)N_NODES * 4);
    int* offs_u = (int*)alloc((size_t)(N_NODES + 1) * 4);
    int* offs_i = (int*)alloc((size_t)(N_NODES + 1) * 4);
    int* cur_u  = (int*)alloc((size_t)N_NODES * 4);
    int* cur_i  = (int*)alloc((size_t)N_NODES * 4);
    int* bsum_u = (int*)alloc((size_t)64 * 4);
    int* bsum_i = (int*)alloc((size_t)64 * 4);
    int* ssrc_u = (int*)alloc((size_t)N_EDGES * 4);
    int* ssrc_i = (int*)alloc((size_t)N_EDGES * 4);
    ushort* xh  = (ushort*)alloc((size_t)N_NODES * 256 * 2);
    ushort* xl  = (ushort*)alloc((size_t)N_NODES * 256 * 2);
    ushort* hh  = (ushort*)alloc((size_t)N_NODES * 256 * 2);
    ushort* hl  = (ushort*)alloc((size_t)N_NODES * 256 * 2);
    ushort* w1h = (ushort*)alloc((size_t)512 * 256 * 2);
    ushort* w1l = (ushort*)alloc((size_t)512 * 256 * 2);
    ushort* w2h = (ushort*)alloc((size_t)128 * 256 * 2);
    ushort* w2l = (ushort*)alloc((size_t)128 * 256 * 2);
    ushort* t1b = (ushort*)alloc((size_t)N_NODES * 256 * 2);  // neighbor term L1 (bf16)
    float*  r1  = (float*)alloc((size_t)N_NODES * 256 * 4);   // root term L1 (f32)
    ushort* t2b = (ushort*)alloc((size_t)N_NODES * 64 * 2);   // neighbor term L2 (bf16)
    float*  r2  = (float*)alloc((size_t)N_NODES * 64 * 4);    // root term L2 (f32)
    float* emb_u = (float*)alloc((size_t)N_NODES * EMB * 4);
    float* emb_i = (float*)alloc((size_t)N_NODES * EMB * 4);

    hipMemsetAsync(cnt_u, 0, (size_t)N_NODES * 4, stream);
    hipMemsetAsync(cnt_i, 0, (size_t)N_NODES * 4, stream);

    const int* u_src = u_ei;
    const int* u_dst = u_ei + N_EDGES;
    const int* i_src = i_ei;
    const int* i_dst = i_ei + N_EDGES;

    int egrid = (N_EDGES + 255) / 256;
    int sgrid = (N_NODES * 64 + 255) / 256;        // one wave per node
    int mgrid64 = (N_NODES + BR - 1) / BR;         // 782
    int cvt_x_grid = (N_NODES * 256 / 4 + 255) / 256;

    // --- CSR build, both graphs (hierarchical scan) ---
    hist_kernel<<<egrid, 256, 0, stream>>>(u_dst, cnt_u, N_EDGES);
    hist_kernel<<<egrid, 256, 0, stream>>>(i_dst, cnt_i, N_EDGES);
    scan_local<<<NBLK, SCAN_B, 0, stream>>>(cnt_u, cur_u, bsum_u, N_NODES);
    scan_local<<<NBLK, SCAN_B, 0, stream>>>(cnt_i, cur_i, bsum_i, N_NODES);
    scan_bsum<<<1, 64, 0, stream>>>(bsum_u, NBLK, offs_u + N_NODES);
    scan_bsum<<<1, 64, 0, stream>>>(bsum_i, NBLK, offs_i + N_NODES);
    scan_add<<<NBLK, SCAN_B, 0, stream>>>(cur_u, bsum_u, offs_u, N_NODES);
    scan_add<<<NBLK, SCAN_B, 0, stream>>>(cur_i, bsum_i, offs_i, N_NODES);
    fill_kernel<<<egrid, 256, 0, stream>>>(u_src, u_dst, cur_u, ssrc_u, N_EDGES);
    fill_kernel<<<egrid, 256, 0, stream>>>(i_src, i_dst, cur_i, ssrc_i, N_EDGES);

    // --- user encoder ---
    cvt_split<<<cvt_x_grid, 256, 0, stream>>>(user_x, xh, xl, N_NODES * 256 / 4);
    cvt_wT<<<(2 * 256 * 256 + 255) / 256, 256, 0, stream>>>(u1_Wn, u1_Wr, w1h, w1l, 256);
    cvt_wT<<<(2 * 64 * 256 + 255) / 256, 256, 0, stream>>>(u2_Wn, u2_Wr, w2h, w2l, 64);
    gemm_bf16x3_v2<<<mgrid64, 256, 0, stream>>>(xh, xl, w1h, w1l, t1b, r1,
                                                N_NODES, 256, 256, 4);
    combine1_kernel<<<sgrid, 256, 0, stream>>>(t1b, r1, offs_u, ssrc_u, u1_b, hh, hl, N_NODES);
    gemm_bf16x3_v2<<<mgrid64, 256, 0, stream>>>(hh, hl, w2h, w2l, t2b, r2,
                                                N_NODES, 64, 64, 1);
    combine2_kernel<<<sgrid, 256, 0, stream>>>(t2b, r2, offs_u, ssrc_u, u2_b, emb_u, N_NODES);

    // --- item encoder (reuse buffers) ---
    cvt_split<<<cvt_x_grid, 256, 0, stream>>>(item_x, xh, xl, N_NODES * 256 / 4);
    cvt_wT<<<(2 * 256 * 256 + 255) / 256, 256, 0, stream>>>(i1_Wn, i1_Wr, w1h, w1l, 256);
    cvt_wT<<<(2 * 64 * 256 + 255) / 256, 256, 0, stream>>>(i2_Wn, i2_Wr, w2h, w2l, 64);
    gemm_bf16x3_v2<<<mgrid64, 256, 0, stream>>>(xh, xl, w1h, w1l, t1b, r1,
                                                N_NODES, 256, 256, 4);
    combine1_kernel<<<sgrid, 256, 0, stream>>>(t1b, r1, offs_i, ssrc_i, i1_b, hh, hl, N_NODES);
    gemm_bf16x3_v2<<<mgrid64, 256, 0, stream>>>(hh, hl, w2h, w2l, t2b, r2,
                                                N_NODES, 64, 64, 1);
    combine2_kernel<<<sgrid, 256, 0, stream>>>(t2b, r2, offs_i, ssrc_i, i2_b, emb_i, N_NODES);

    // --- scoring head ---
    head_kernel<<<(N_NODES + 255) / 256, 256, 0, stream>>>(emb_u, emb_i, head_W,
                                                           head_b, out, N_NODES);
}

// Round 15
// 866.842 us; speedup vs baseline: 1.1361x; 1.1361x over previous
//
#include <hip/hip_runtime.h>
#include <cstdint>
#include <cstddef>

#define N_NODES 50000
#define N_EDGES 800000
#define IN_DIM 256
#define HID 256
#define EMB 64
#define SCAN_B 1024
#define NBLK ((N_NODES + SCAN_B - 1) / SCAN_B)   // 49

typedef __attribute__((ext_vector_type(8))) short bf16x8v;   // 8 bf16 in 4 VGPRs
typedef __attribute__((ext_vector_type(4))) float f32x4v;    // MFMA accumulator

// ---- manual bf16 RNE convert ------------------------------------------------
__device__ inline ushort f2bf(float f) {
    uint32_t u = __float_as_uint(f);
    uint32_t r = (u + 0x7FFFu + ((u >> 16) & 1u)) >> 16;
    return (ushort)r;
}
__device__ inline float bf2f(ushort b) {
    return __uint_as_float((uint32_t)b << 16);
}

// ---------------------------------------------------------------------------
// CSR build: histogram -> hierarchical exclusive scan -> fill sorted src list
// ---------------------------------------------------------------------------
__global__ void hist_kernel(const int* __restrict__ dst, int* __restrict__ cnt, int E) {
    int e = blockIdx.x * blockDim.x + threadIdx.x;
    if (e < E) atomicAdd(&cnt[dst[e]], 1);
}

__global__ void scan_local(const int* __restrict__ cnt, int* __restrict__ loc,
                           int* __restrict__ bsum, int n) {
    __shared__ int buf[SCAN_B];
    int tid = threadIdx.x;
    int i = blockIdx.x * SCAN_B + tid;
    int v = (i < n) ? cnt[i] : 0;
    buf[tid] = v;
    __syncthreads();
    #pragma unroll
    for (int off = 1; off < SCAN_B; off <<= 1) {
        int t = (tid >= off) ? buf[tid - off] : 0;
        __syncthreads();
        buf[tid] += t;
        __syncthreads();
    }
    if (i < n) loc[i] = buf[tid] - v;
    if (tid == SCAN_B - 1) bsum[blockIdx.x] = buf[SCAN_B - 1];
}

__global__ void scan_bsum(int* __restrict__ bsum, int nb, int* __restrict__ total_out) {
    __shared__ int b[64];
    int tid = threadIdx.x;
    int v = (tid < nb) ? bsum[tid] : 0;
    b[tid] = v;
    __syncthreads();
    #pragma unroll
    for (int off = 1; off < 64; off <<= 1) {
        int t = (tid >= off) ? b[tid - off] : 0;
        __syncthreads();
        b[tid] += t;
        __syncthreads();
    }
    if (tid < nb) bsum[tid] = b[tid] - v;
    if (tid == 63) *total_out = b[63];
}

__global__ void scan_add(int* __restrict__ loc_cursor, const int* __restrict__ bsum,
                         int* __restrict__ offs, int n) {
    int i = blockIdx.x * SCAN_B + threadIdx.x;
    if (i < n) {
        int o = loc_cursor[i] + bsum[blockIdx.x];
        offs[i] = o;
        loc_cursor[i] = o;
    }
}

__global__ void fill_kernel(const int* __restrict__ src, const int* __restrict__ dst,
                            int* __restrict__ cursor, int* __restrict__ ssrc, int E) {
    int e = blockIdx.x * blockDim.x + threadIdx.x;
    if (e < E) {
        int d = dst[e];
        int pos = atomicAdd(&cursor[d], 1);
        ssrc[pos] = src[e];
    }
}

// ---------------------------------------------------------------------------
// cvt_split: f32 [n] -> bf16 hi + bf16 lo (residual). One thread per 4 elems.
// ---------------------------------------------------------------------------
__global__ void cvt_split(const float* __restrict__ x, ushort* __restrict__ xh,
                          ushort* __restrict__ xl, int n4) {
    int i = blockIdx.x * blockDim.x + threadIdx.x;
    if (i >= n4) return;
    float4 v = ((const float4*)x)[i];
    ushort4 h, l;
    h.x = f2bf(v.x); l.x = f2bf(v.x - bf2f(h.x));
    h.y = f2bf(v.y); l.y = f2bf(v.y - bf2f(h.y));
    h.z = f2bf(v.z); l.z = f2bf(v.z - bf2f(h.z));
    h.w = f2bf(v.w); l.w = f2bf(v.w - bf2f(h.w));
    ((ushort4*)xh)[i] = h;
    ((ushort4*)xl)[i] = l;
}

// ---------------------------------------------------------------------------
// cvt_wT: build transposed+split weight BT[n][k] (k=256) from B1,B2 [256,Nhalf]
// ---------------------------------------------------------------------------
__global__ void cvt_wT(const float* __restrict__ B1, const float* __restrict__ B2,
                       ushort* __restrict__ th, ushort* __restrict__ tl, int Nhalf) {
    int idx = blockIdx.x * blockDim.x + threadIdx.x;   // n*256 + k
    if (idx >= 2 * Nhalf * 256) return;
    int nn = idx >> 8;
    int k  = idx & 255;
    const float* Bp = (nn < Nhalf) ? B1 : B2;
    int col = (nn < Nhalf) ? nn : nn - Nhalf;
    float v = Bp[(size_t)k * Nhalf + col];
    ushort h = f2bf(v);
    th[idx] = h;
    tl[idx] = f2bf(v - bf2f(h));
}

// ---------------------------------------------------------------------------
// bf16x3 split MFMA GEMM v3 = v1 layout (0 bank conflicts measured) +
//   (a) coalesced staging map: 4 lanes share one 64B row-chunk
//   (b) double-buffered A staging, issue-early/write-late (T14), ONE barrier/K-step
// cols < nsplit -> Cb (bf16, ld=nsplit); cols >= nsplit -> Cf (f32, ld=ldf)
// Block 128x128 tile, 4 waves 2x2, wave 64x64 = 4x4 frags, K-step 32, LDS 32KB.
// ---------------------------------------------------------------------------
__global__ __launch_bounds__(256) void gemm_bf16x3_v3(
        const ushort* __restrict__ Ah, const ushort* __restrict__ Al,
        const ushort* __restrict__ BTh, const ushort* __restrict__ BTl,
        ushort* __restrict__ Cb, float* __restrict__ Cf,
        int M, int nsplit, int ldf) {
    __shared__ ushort As[2][2][128 * 32];   // [dbuf][hi/lo][row*32 + swz k], 32 KiB

    int tid  = threadIdx.x;
    int lane = tid & 63;
    int wv   = tid >> 6;        // 0..3
    int wm   = wv >> 1;         // wave row
    int wn   = wv & 1;          // wave col
    int rowBase = blockIdx.x * 128;
    int colBase = blockIdx.y * 128;

    // staging map (coalesced): matrix sm = tid>>7; t = tid&127
    //   slot = t&3 (16B), rows = (t>>2) + {0,32,64,96}
    //   -> 4 consecutive lanes cover one row's 64B k-chunk (full cache lines)
    int sm   = tid >> 7;
    int t    = tid & 127;
    int slot = t & 3;
    int r0   = t >> 2;
    const ushort* Ag = sm ? Al : Ah;

    uint4 st[4];
    auto issue = [&](int k0) {
        #pragma unroll
        for (int j = 0; j < 4; ++j) {
            int row = r0 + j * 32;
            int gr  = rowBase + row;
            st[j] = (gr < M)
                  ? *(const uint4*)(Ag + (size_t)gr * 256 + k0 * 32 + slot * 8)
                  : make_uint4(0u, 0u, 0u, 0u);
        }
    };
    auto stwrite = [&](int buf) {
        #pragma unroll
        for (int j = 0; j < 4; ++j) {
            int row = r0 + j * 32;
            int sx  = (row >> 1) & 3;              // v1 swizzle (measured 0 conflicts)
            *(uint4*)&As[buf][sm][row * 32 + ((slot ^ sx) * 8)] = st[j];
        }
    };

    int fr = lane & 15;         // A row-in-frag / B col / C col
    int fc = lane >> 4;         // k-slot (8 elems) / C row group
    int axor = (fr >> 1) & 3;   // matches (row>>1)&3 since row = 16*a + fr, a*16 ≡ 0 mod 4

    f32x4v zero4 = {0.f, 0.f, 0.f, 0.f};
    f32x4v acc[4][4];
    #pragma unroll
    for (int a = 0; a < 4; ++a)
        #pragma unroll
        for (int b = 0; b < 4; ++b) acc[a][b] = zero4;

    issue(0);
    stwrite(0);
    __syncthreads();

    for (int k0 = 0; k0 < 8; ++k0) {
        int cur = k0 & 1;
        if (k0 < 7) issue(k0 + 1);          // HBM latency hides under compute below

        bf16x8v afh[4], afl[4];
        #pragma unroll
        for (int mf = 0; mf < 4; ++mf) {
            int row  = wm * 64 + mf * 16 + fr;
            int addr = row * 32 + ((fc ^ axor) * 8);
            afh[mf] = *(const bf16x8v*)&As[cur][0][addr];
            afl[mf] = *(const bf16x8v*)&As[cur][1][addr];
        }
        #pragma unroll
        for (int nf = 0; nf < 4; ++nf) {
            int col = colBase + wn * 64 + nf * 16 + fr;
            size_t boff = (size_t)col * 256 + k0 * 32 + fc * 8;
            bf16x8v bfh = *(const bf16x8v*)(BTh + boff);
            bf16x8v bfl = *(const bf16x8v*)(BTl + boff);
            #pragma unroll
            for (int mf = 0; mf < 4; ++mf) {
                acc[mf][nf] = __builtin_amdgcn_mfma_f32_16x16x32_bf16(
                                  afh[mf], bfh, acc[mf][nf], 0, 0, 0);
                acc[mf][nf] = __builtin_amdgcn_mfma_f32_16x16x32_bf16(
                                  afh[mf], bfl, acc[mf][nf], 0, 0, 0);
                acc[mf][nf] = __builtin_amdgcn_mfma_f32_16x16x32_bf16(
                                  afl[mf], bfh, acc[mf][nf], 0, 0, 0);
            }
        }

        if (k0 < 7) stwrite((k0 + 1) & 1);  // loads have had ~compute-time to land
        __syncthreads();                    // ONE barrier per K-step
    }

    // C/D layout (m89-verified): col = lane&15, row = (lane>>4)*4 + reg
    #pragma unroll
    for (int mf = 0; mf < 4; ++mf) {
        #pragma unroll
        for (int nf = 0; nf < 4; ++nf) {
            int col = colBase + wn * 64 + nf * 16 + fr;
            #pragma unroll
            for (int r = 0; r < 4; ++r) {
                int row = rowBase + wm * 64 + mf * 16 + fc * 4 + r;
                if (row < M) {
                    float v = acc[mf][nf][r];
                    if (col < nsplit)
                        Cb[(size_t)row * nsplit + col] = f2bf(v);
                    else
                        Cf[(size_t)row * ldf + (col - nsplit)] = v;
                }
            }
        }
    }
}

// ---------------------------------------------------------------------------
// combine1: h = relu( segmean(t1b) + r1 + b1 ), output split to bf16 hi/lo.
// ---------------------------------------------------------------------------
__global__ void combine1_kernel(const ushort* __restrict__ t1b,
                                const float* __restrict__ r1,
                                const int* __restrict__ offs,
                                const int* __restrict__ ssrc,
                                const float* __restrict__ b1,
                                ushort* __restrict__ hh, ushort* __restrict__ hl,
                                int n) {
    int gtid = blockIdx.x * blockDim.x + threadIdx.x;
    int node = gtid >> 6;
    int lane = gtid & 63;
    if (node >= n) return;
    int beg = offs[node];
    int end = offs[node + 1];
    const ushort4* t = (const ushort4*)t1b;   // row stride = 64 ushort4
    float4 s = make_float4(0.f, 0.f, 0.f, 0.f);
    int e = beg;
    for (; e + 1 < end; e += 2) {
        int s0 = ssrc[e];
        int s1 = ssrc[e + 1];
        ushort4 q0 = t[(size_t)s0 * 64 + lane];
        ushort4 q1 = t[(size_t)s1 * 64 + lane];
        s.x += bf2f(q0.x) + bf2f(q1.x);
        s.y += bf2f(q0.y) + bf2f(q1.y);
        s.z += bf2f(q0.z) + bf2f(q1.z);
        s.w += bf2f(q0.w) + bf2f(q1.w);
    }
    if (e < end) {
        ushort4 q0 = t[(size_t)ssrc[e] * 64 + lane];
        s.x += bf2f(q0.x); s.y += bf2f(q0.y);
        s.z += bf2f(q0.z); s.w += bf2f(q0.w);
    }
    int deg = end - beg;
    float inv = 1.0f / (float)(deg > 0 ? deg : 1);
    float4 r = ((const float4*)r1)[(size_t)node * 64 + lane];
    float4 bb = ((const float4*)b1)[lane];
    float o0 = s.x * inv + r.x + bb.x;
    float o1 = s.y * inv + r.y + bb.y;
    float o2 = s.z * inv + r.z + bb.z;
    float o3 = s.w * inv + r.w + bb.w;
    o0 = o0 > 0.f ? o0 : 0.f;
    o1 = o1 > 0.f ? o1 : 0.f;
    o2 = o2 > 0.f ? o2 : 0.f;
    o3 = o3 > 0.f ? o3 : 0.f;
    ushort4 h, l;
    h.x = f2bf(o0); l.x = f2bf(o0 - bf2f(h.x));
    h.y = f2bf(o1); l.y = f2bf(o1 - bf2f(h.y));
    h.z = f2bf(o2); l.z = f2bf(o2 - bf2f(h.z));
    h.w = f2bf(o3); l.w = f2bf(o3 - bf2f(h.w));
    ((ushort4*)hh)[(size_t)node * 64 + lane] = h;
    ((ushort4*)hl)[(size_t)node * 64 + lane] = l;
}

// ---------------------------------------------------------------------------
// combine2: emb = segmean(t2b) + r2 + b2.
// ---------------------------------------------------------------------------
__global__ void combine2_kernel(const ushort* __restrict__ t2b,
                                const float* __restrict__ r2,
                                const int* __restrict__ offs,
                                const int* __restrict__ ssrc,
                                const float* __restrict__ b2,
                                float* __restrict__ emb, int n) {
    int gtid = blockIdx.x * blockDim.x + threadIdx.x;
    int node = gtid >> 6;
    int lane = gtid & 63;
    if (node >= n) return;
    int beg = offs[node];
    int end = offs[node + 1];
    float s = 0.f;
    int e = beg;
    for (; e + 1 < end; e += 2) {
        int s0 = ssrc[e];
        int s1 = ssrc[e + 1];
        float v0 = bf2f(t2b[(size_t)s0 * 64 + lane]);
        float v1 = bf2f(t2b[(size_t)s1 * 64 + lane]);
        s += v0 + v1;
    }
    if (e < end) s += bf2f(t2b[(size_t)ssrc[e] * 64 + lane]);
    int deg = end - beg;
    float inv = 1.0f / (float)(deg > 0 ? deg : 1);
    emb[(size_t)node * 64 + lane] =
        s * inv + r2[(size_t)node * 64 + lane] + b2[lane];
}

// ---------------------------------------------------------------------------
// Head
// ---------------------------------------------------------------------------
__global__ void head_kernel(const float* __restrict__ eu, const float* __restrict__ ei,
                            const float* __restrict__ hW, const float* __restrict__ hb,
                            float* __restrict__ out, int n) {
    __shared__ float w[128];
    __shared__ float b0;
    if (threadIdx.x < 128) w[threadIdx.x] = hW[threadIdx.x];
    if (threadIdx.x == 0) b0 = hb[0];
    __syncthreads();
    int i = blockIdx.x * blockDim.x + threadIdx.x;
    if (i >= n) return;
    const float4* a = (const float4*)(eu + (size_t)i * 64);
    const float4* c = (const float4*)(ei + (size_t)i * 64);
    float s = b0;
    #pragma unroll
    for (int j = 0; j < 16; ++j) {
        float4 v = a[j];
        s += v.x * w[j * 4 + 0] + v.y * w[j * 4 + 1] + v.z * w[j * 4 + 2] + v.w * w[j * 4 + 3];
    }
    #pragma unroll
    for (int j = 0; j < 16; ++j) {
        float4 v = c[j];
        s += v.x * w[64 + j * 4 + 0] + v.y * w[64 + j * 4 + 1] + v.z * w[64 + j * 4 + 2] + v.w * w[64 + j * 4 + 3];
    }
    out[i] = 1.0f / (1.0f + __expf(-s));
}

// ---------------------------------------------------------------------------
extern "C" void kernel_launch(void* const* d_in, const int* in_sizes, int n_in,
                              void* d_out, int out_size, void* d_ws, size_t ws_size,
                              hipStream_t stream) {
    const float* user_x = (const float*)d_in[0];
    const float* item_x = (const float*)d_in[1];
    const int*   u_ei   = (const int*)d_in[2];
    const int*   i_ei   = (const int*)d_in[3];
    const float* u1_Wn = (const float*)d_in[4];
    const float* u1_Wr = (const float*)d_in[5];
    const float* u1_b  = (const float*)d_in[6];
    const float* u2_Wn = (const float*)d_in[7];
    const float* u2_Wr = (const float*)d_in[8];
    const float* u2_b  = (const float*)d_in[9];
    const float* i1_Wn = (const float*)d_in[10];
    const float* i1_Wr = (const float*)d_in[11];
    const float* i1_b  = (const float*)d_in[12];
    const float* i2_Wn = (const float*)d_in[13];
    const float* i2_Wr = (const float*)d_in[14];
    const float* i2_b  = (const float*)d_in[15];
    const float* head_W = (const float*)d_in[16];
    const float* head_b = (const float*)d_in[17];
    float* out = (float*)d_out;

    // Workspace carve-up (256B aligned). Total ~231 MB.
    char* p = (char*)d_ws;
    auto alloc = [&](size_t bytes) -> void* {
        void* r = (void*)p;
        p += (bytes + 255) & ~(size_t)255;
        return r;
    };
    int* cnt_u  = (int*)alloc((size_t)N_NODES * 4);
    int* cnt_i  = (int*)alloc((size_t)N_NODES * 4);
    int* offs_u = (int*)alloc((size_t)(N_NODES + 1) * 4);
    int* offs_i = (int*)alloc((size_t)(N_NODES + 1) * 4);
    int* cur_u  = (int*)alloc((size_t)N_NODES * 4);
    int* cur_i  = (int*)alloc((size_t)N_NODES * 4);
    int* bsum_u = (int*)alloc((size_t)64 * 4);
    int* bsum_i = (int*)alloc((size_t)64 * 4);
    int* ssrc_u = (int*)alloc((size_t)N_EDGES * 4);
    int* ssrc_i = (int*)alloc((size_t)N_EDGES * 4);
    ushort* xh  = (ushort*)alloc((size_t)N_NODES * 256 * 2);
    ushort* xl  = (ushort*)alloc((size_t)N_NODES * 256 * 2);
    ushort* hh  = (ushort*)alloc((size_t)N_NODES * 256 * 2);
    ushort* hl  = (ushort*)alloc((size_t)N_NODES * 256 * 2);
    ushort* w1h = (ushort*)alloc((size_t)512 * 256 * 2);
    ushort* w1l = (ushort*)alloc((size_t)512 * 256 * 2);
    ushort* w2h = (ushort*)alloc((size_t)128 * 256 * 2);
    ushort* w2l = (ushort*)alloc((size_t)128 * 256 * 2);
    ushort* t1b = (ushort*)alloc((size_t)N_NODES * 256 * 2);  // neighbor term L1 (bf16)
    float*  r1  = (float*)alloc((size_t)N_NODES * 256 * 4);   // root term L1 (f32)
    ushort* t2b = (ushort*)alloc((size_t)N_NODES * 64 * 2);   // neighbor term L2 (bf16)
    float*  r2  = (float*)alloc((size_t)N_NODES * 64 * 4);    // root term L2 (f32)
    float* emb_u = (float*)alloc((size_t)N_NODES * EMB * 4);
    float* emb_i = (float*)alloc((size_t)N_NODES * EMB * 4);

    hipMemsetAsync(cnt_u, 0, (size_t)N_NODES * 4, stream);
    hipMemsetAsync(cnt_i, 0, (size_t)N_NODES * 4, stream);

    const int* u_src = u_ei;
    const int* u_dst = u_ei + N_EDGES;
    const int* i_src = i_ei;
    const int* i_dst = i_ei + N_EDGES;

    int egrid = (N_EDGES + 255) / 256;
    int sgrid = (N_NODES * 64 + 255) / 256;        // one wave per node
    int mgrid128 = (N_NODES + 127) / 128;          // 391
    int cvt_x_grid = (N_NODES * 256 / 4 + 255) / 256;

    // --- CSR build, both graphs (hierarchical scan) ---
    hist_kernel<<<egrid, 256, 0, stream>>>(u_dst, cnt_u, N_EDGES);
    hist_kernel<<<egrid, 256, 0, stream>>>(i_dst, cnt_i, N_EDGES);
    scan_local<<<NBLK, SCAN_B, 0, stream>>>(cnt_u, cur_u, bsum_u, N_NODES);
    scan_local<<<NBLK, SCAN_B, 0, stream>>>(cnt_i, cur_i, bsum_i, N_NODES);
    scan_bsum<<<1, 64, 0, stream>>>(bsum_u, NBLK, offs_u + N_NODES);
    scan_bsum<<<1, 64, 0, stream>>>(bsum_i, NBLK, offs_i + N_NODES);
    scan_add<<<NBLK, SCAN_B, 0, stream>>>(cur_u, bsum_u, offs_u, N_NODES);
    scan_add<<<NBLK, SCAN_B, 0, stream>>>(cur_i, bsum_i, offs_i, N_NODES);
    fill_kernel<<<egrid, 256, 0, stream>>>(u_src, u_dst, cur_u, ssrc_u, N_EDGES);
    fill_kernel<<<egrid, 256, 0, stream>>>(i_src, i_dst, cur_i, ssrc_i, N_EDGES);

    // --- user encoder ---
    cvt_split<<<cvt_x_grid, 256, 0, stream>>>(user_x, xh, xl, N_NODES * 256 / 4);
    cvt_wT<<<(2 * 256 * 256 + 255) / 256, 256, 0, stream>>>(u1_Wn, u1_Wr, w1h, w1l, 256);
    cvt_wT<<<(2 * 64 * 256 + 255) / 256, 256, 0, stream>>>(u2_Wn, u2_Wr, w2h, w2l, 64);
    {
        dim3 g(mgrid128, 4);   // cols 0..255 -> t1b (bf16), 256..511 -> r1 (f32)
        gemm_bf16x3_v3<<<g, 256, 0, stream>>>(xh, xl, w1h, w1l, t1b, r1, N_NODES, 256, 256);
    }
    combine1_kernel<<<sgrid, 256, 0, stream>>>(t1b, r1, offs_u, ssrc_u, u1_b, hh, hl, N_NODES);
    {
        dim3 g(mgrid128, 1);   // cols 0..63 -> t2b (bf16), 64..127 -> r2 (f32)
        gemm_bf16x3_v3<<<g, 256, 0, stream>>>(hh, hl, w2h, w2l, t2b, r2, N_NODES, 64, 64);
    }
    combine2_kernel<<<sgrid, 256, 0, stream>>>(t2b, r2, offs_u, ssrc_u, u2_b, emb_u, N_NODES);

    // --- item encoder (reuse buffers) ---
    cvt_split<<<cvt_x_grid, 256, 0, stream>>>(item_x, xh, xl, N_NODES * 256 / 4);
    cvt_wT<<<(2 * 256 * 256 + 255) / 256, 256, 0, stream>>>(i1_Wn, i1_Wr, w1h, w1l, 256);
    cvt_wT<<<(2 * 64 * 256 + 255) / 256, 256, 0, stream>>>(i2_Wn, i2_Wr, w2h, w2l, 64);
    {
        dim3 g(mgrid128, 4);
        gemm_bf16x3_v3<<<g, 256, 0, stream>>>(xh, xl, w1h, w1l, t1b, r1, N_NODES, 256, 256);
    }
    combine1_kernel<<<sgrid, 256, 0, stream>>>(t1b, r1, offs_i, ssrc_i, i1_b, hh, hl, N_NODES);
    {
        dim3 g(mgrid128, 1);
        gemm_bf16x3_v3<<<g, 256, 0, stream>>>(hh, hl, w2h, w2l, t2b, r2, N_NODES, 64, 64);
    }
    combine2_kernel<<<sgrid, 256, 0, stream>>>(t2b, r2, offs_i, ssrc_i, i2_b, emb_i, N_NODES);

    // --- scoring head ---
    head_kernel<<<(N_NODES + 255) / 256, 256, 0, stream>>>(emb_u, emb_i, head_W,
                                                           head_b, out, N_NODES);
}